// Round 17
// baseline (51.030 us; speedup 1.0000x reference)
//
#include <hip/hip_runtime.h>

#define B_   2
#define H_   16
#define S_   2048
#define D_   64
#define BQ   128    // q rows per block (16 per wave, 8 waves)
#define BK   64
#define NW   8
// fold 1/sqrt(64) * log2(e) into Q so softmax works in exp2 domain
#define QSCALE 0.18033688011112042f
#define DEFER_THR 8.0f

typedef _Float16 f16x4 __attribute__((ext_vector_type(4)));
typedef _Float16 f16x8 __attribute__((ext_vector_type(8)));
typedef float    f32x4 __attribute__((ext_vector_type(4)));

typedef const unsigned int __attribute__((address_space(1))) gu32;
typedef unsigned int       __attribute__((address_space(3))) lu32;

#define KBYTES_PER_HEAD (S_ * 128)                       // 256 KB f16 per head per tensor
#define WS_V_OFF ((size_t)B_ * H_ * KBYTES_PER_HEAD)     // 8.4 MB
#define WS_NEED  (2 * WS_V_OFF)

// ---------------- fused prepass (verified, unchanged): K -> swizzled f16 tiles,
// V -> transposed swizzled f16 tiles
__global__ __launch_bounds__(256) void prep_kv(const float* __restrict__ K,
                                               const float* __restrict__ V,
                                               char* __restrict__ ws)
{
    if (blockIdx.x < (B_ * H_ * S_ * 8) / 256) {
        const int gidx = blockIdx.x * 256 + threadIdx.x;
        const int gcol = gidx & 7;
        const int srow = gidx >> 3;                      // bh*S + s
        const float4* src = (const float4*)(K + (size_t)srow * D_ + gcol * 8);
        float4 a = src[0], b = src[1];
        f16x8 h;
        h[0] = (_Float16)a.x; h[1] = (_Float16)a.y; h[2] = (_Float16)a.z; h[3] = (_Float16)a.w;
        h[4] = (_Float16)b.x; h[5] = (_Float16)b.y; h[6] = (_Float16)b.z; h[7] = (_Float16)b.w;
        const int s  = srow & (S_ - 1);
        const int bh = srow >> 11;
        size_t off = (size_t)bh * KBYTES_PER_HEAD + (size_t)(s >> 6) * 8192
                   + (s & 63) * 128 + ((gcol ^ (s & 7)) << 4);
        *(f16x8*)(ws + off) = h;
    } else {
        __shared__ _Float16 Vl[64][72];
        const int tile = blockIdx.x - (B_ * H_ * S_ * 8) / 256;  // bh*32 + t
        const int bh = tile >> 5, t = tile & 31;
        const float* vb = V + ((size_t)bh * S_ + t * 64) * D_;
        const int tid = threadIdx.x;
        #pragma unroll
        for (int it = 0; it < 2; ++it) {
            const int row = (tid >> 3) + it * 32;
            const int c8  = (tid & 7) * 8;
            const float4* p = (const float4*)(vb + row * D_ + c8);
            float4 a = p[0], b = p[1];
            f16x8 h;
            h[0] = (_Float16)a.x; h[1] = (_Float16)a.y; h[2] = (_Float16)a.z; h[3] = (_Float16)a.w;
            h[4] = (_Float16)b.x; h[5] = (_Float16)b.y; h[6] = (_Float16)b.z; h[7] = (_Float16)b.w;
            *(f16x8*)&Vl[row][c8] = h;
        }
        __syncthreads();
        char* out = ws + WS_V_OFF + (size_t)bh * KBYTES_PER_HEAD + t * 8192;
        #pragma unroll
        for (int it = 0; it < 2; ++it) {
            const int task = tid + it * 256;
            const int d = task >> 3, kg = task & 7;
            f16x8 h;
            #pragma unroll
            for (int j = 0; j < 8; ++j) h[j] = Vl[kg * 8 + j][d];
            *(f16x8*)(out + d * 128 + ((kg ^ (d & 7)) << 4)) = h;
        }
    }
}

// ---------------- pipeline pieces (layouts identical to verified R8 kernel) ----------------

// QK^T swapped: A = K rows, B = Q  ->  accS[k-sub = g*4+r][q = l15]
template<bool MASK>
__device__ __forceinline__ void qk_tile(
    const _Float16* __restrict__ Kb, const f16x8 aq[2], f32x4 (&accS)[4],
    int g, int l15, int sx, int dq)
{
    #pragma unroll
    for (int s = 0; s < 4; ++s) accS[s] = (f32x4){0.f, 0.f, 0.f, 0.f};
    __builtin_amdgcn_s_setprio(1);
    #pragma unroll
    for (int sub = 0; sub < 4; ++sub) {
        if (MASK && (sub * 16 > dq + 15)) continue;      // wave-uniform fully-masked sub
        #pragma unroll
        for (int kc = 0; kc < 2; ++kc) {
            f16x8 ak = *(const f16x8*)(Kb + ((sub * 16 + l15) * 64 + (((kc * 4 + g) ^ sx) << 3)));
            accS[sub] = __builtin_amdgcn_mfma_f32_16x16x32_f16(ak, aq[kc], accS[sub], 0, 0, 0);
        }
    }
    __builtin_amdgcn_s_setprio(0);
}

// online softmax (exp2 domain, defer-max) + PV on the PREVIOUS tile's scores
template<bool MASK>
__device__ __forceinline__ void smpv_tile(
    const _Float16* __restrict__ SMb, _Float16 (*__restrict__ Plw)[72],
    f32x4 (&accS)[4], f32x4 accO[4], float& m_r, float& l_r,
    int g, int l15, int sx, int dq)
{
    const _Float16* Vb = SMb + 4096;

    auto msk = [&](int sub, int r) -> float {
        float s = accS[sub][r];
        if (MASK) {
            if (sub * 16 > dq + 15) s = -1e30f;
            else if (sub * 16 + 15 > dq) {
                if (sub * 16 + g * 4 + r > dq + l15) s = -1e30f;
            }
        }
        return s;
    };

    float pmax = -1e30f;
    #pragma unroll
    for (int sub = 0; sub < 4; ++sub)
        #pragma unroll
        for (int r = 0; r < 4; ++r) pmax = fmaxf(pmax, msk(sub, r));

    // defer-max (T13): wave-uniform ballot; common case no cross-lane ops
    if (!__all(pmax <= m_r + DEFER_THR)) {
        float mx = pmax;
        mx = fmaxf(mx, __shfl_xor(mx, 16));
        mx = fmaxf(mx, __shfl_xor(mx, 32));
        const float mnew  = fmaxf(m_r, mx);
        const float alpha = __builtin_amdgcn_exp2f(m_r - mnew);
        l_r *= alpha;
        #pragma unroll
        for (int d = 0; d < 4; ++d)
            #pragma unroll
            for (int r = 0; r < 4; ++r) accO[d][r] *= alpha;
        m_r = mnew;
    }

    // exp2 with (stale-by-<=THR) m_r: values bounded by 2^THR = 256, f16-safe
    float rs = 0.f;
    #pragma unroll
    for (int sub = 0; sub < 4; ++sub) {
        float p0 = __builtin_amdgcn_exp2f(msk(sub, 0) - m_r);
        float p1 = __builtin_amdgcn_exp2f(msk(sub, 1) - m_r);
        float p2 = __builtin_amdgcn_exp2f(msk(sub, 2) - m_r);
        float p3 = __builtin_amdgcn_exp2f(msk(sub, 3) - m_r);
        rs += (p0 + p1) + (p2 + p3);
        f16x4 q4;
        q4[0] = (_Float16)p0; q4[1] = (_Float16)p1;
        q4[2] = (_Float16)p2; q4[3] = (_Float16)p3;
        *(f16x4*)&Plw[l15][sub * 16 + g * 4] = q4;       // row q=l15, col k
    }
    l_r += rs;

    asm volatile("s_waitcnt lgkmcnt(0)" ::: "memory");   // wave-local Pl write->read fence
    __builtin_amdgcn_sched_barrier(0);

    f16x8 pb0 = *(const f16x8*)&Plw[l15][g * 8];
    f16x8 pb1 = *(const f16x8*)&Plw[l15][32 + g * 8];

    // PV swapped: A = V^T rows (d), B = P^T -> accO[dsub]: d = dsub*16+g*4+r, q = l15
    __builtin_amdgcn_s_setprio(1);
    #pragma unroll
    for (int d = 0; d < 4; ++d) {
        f16x8 av0 = *(const f16x8*)(Vb + ((d * 16 + l15) * 64 + (((0 * 4 + g) ^ sx) << 3)));
        accO[d] = __builtin_amdgcn_mfma_f32_16x16x32_f16(av0, pb0, accO[d], 0, 0, 0);
        f16x8 av1 = *(const f16x8*)(Vb + ((d * 16 + l15) * 64 + (((1 * 4 + g) ^ sx) << 3)));
        accO[d] = __builtin_amdgcn_mfma_f32_16x16x32_f16(av1, pb1, accO[d], 0, 0, 0);
    }
    __builtin_amdgcn_s_setprio(0);
}

__global__ __launch_bounds__(512, 4) void attn_main(
    const float* __restrict__ Q, const char* __restrict__ ws, float* __restrict__ O)
{
    __shared__ _Float16 SM[3][8192];        // triple buffer: [ K 0..4095 | V 4096..8191 ]
    __shared__ _Float16 Pl[NW][16][72];

    const int tid  = threadIdx.x;
    const int lane = tid & 63;
    const int w    = tid >> 6;              // wave 0..7
    const int g    = lane >> 4;
    const int l15  = lane & 15;
    const int sx   = l15 & 7;

    // Balanced heavy+light strip pairing with head->XCD affinity (id%8 = bh%8)
    const int id    = blockIdx.x;
    const int bh    = id & 31;
    const int qi    = id >> 5;              // 0..15
    const int qt    = (id < 256) ? (15 - qi) : (qi - 8);
    const int qbase = qt * BQ;

    const char* kbase = ws + (size_t)bh * KBYTES_PER_HEAD;
    const char* vbase = ws + WS_V_OFF + (size_t)bh * KBYTES_PER_HEAD;

    // hoist Q fragments, pre-scaled into exp2 domain
    f16x8 aq[2];
    {
        const float* qrow = Q + ((size_t)bh * S_ + qbase + w * 16 + l15) * D_;
        #pragma unroll
        for (int kc = 0; kc < 2; ++kc) {
            const float4* p = (const float4*)(qrow + kc * 32 + g * 8);
            float4 x0 = p[0], x1 = p[1];
            f16x8 h;
            h[0] = (_Float16)(x0.x * QSCALE); h[1] = (_Float16)(x0.y * QSCALE);
            h[2] = (_Float16)(x0.z * QSCALE); h[3] = (_Float16)(x0.w * QSCALE);
            h[4] = (_Float16)(x1.x * QSCALE); h[5] = (_Float16)(x1.y * QSCALE);
            h[6] = (_Float16)(x1.z * QSCALE); h[7] = (_Float16)(x1.w * QSCALE);
            aq[kc] = h;
        }
    }

    f32x4 accO[4];
    #pragma unroll
    for (int i = 0; i < 4; ++i) accO[i] = (f32x4){0.f, 0.f, 0.f, 0.f};
    float m_r = -1e30f, l_r = 0.f;
    f32x4 accSA[4], accSB[4];

    const int nt  = 2 * qt + 2;             // 64-wide tiles; last two straddle the diagonal
    const int dqw = qbase + w * 16;         // wave q-row base

    // rotating buffer pointers: bQK = tile t, bPV = tile t-1, bST = stage target (t+1)
    _Float16* bQK = &SM[0][0];
    _Float16* bST = &SM[1][0];
    _Float16* bPV = &SM[2][0];

    // stage tile t into dst: 16 x 1KB chunks, 2 per wave (pre-swizzled source, linear dest)
    auto STAGE = [&](int t, _Float16* dst) {
        #pragma unroll
        for (int i = 0; i < 2; ++i) {
            const int c = w * 2 + i;
            const char* src = (c < 8 ? kbase + (size_t)t * 8192 + c * 1024
                                     : vbase + (size_t)t * 8192 + (c - 8) * 1024) + lane * 16;
            __builtin_amdgcn_global_load_lds((gu32*)src, (lu32*)(dst + c * 512), 16, 0, 0);
        }
    };
    auto SYNC = []() {
        asm volatile("s_waitcnt vmcnt(0)" ::: "memory");
        __builtin_amdgcn_s_barrier();
    };
    auto ROT = [&]() { _Float16* tmp = bPV; bPV = bQK; bQK = bST; bST = tmp; };

    STAGE(0, bQK);

    // ---- window 0: QK(0) -> A
    SYNC();
    STAGE(1, bST);
    if (qt == 0) qk_tile<true >(bQK, aq, accSA, g, l15, sx, dqw);
    else         qk_tile<false>(bQK, aq, accSA, g, l15, sx, 0);
    ROT();

    // ---- window 1: QK(1) -> B, SM+PV(0) from A
    SYNC();
    if (nt > 2) STAGE(2, bST);
    if (qt == 0) {
        qk_tile<true >(bQK, aq, accSB, g, l15, sx, dqw - 64);
        smpv_tile<true >(bPV, Pl[w], accSA, accO, m_r, l_r, g, l15, sx, dqw);
    } else {
        qk_tile<false>(bQK, aq, accSB, g, l15, sx, 0);
        smpv_tile<false>(bPV, Pl[w], accSA, accO, m_r, l_r, g, l15, sx, 0);
    }
    ROT();

    // ---- steady windows: tiles 2i (->A) and 2i+1 (->B), all unmasked
    for (int i = 1; i < qt; ++i) {
        const int t0 = 2 * i;
        SYNC();
        STAGE(t0 + 1, bST);
        qk_tile<false>(bQK, aq, accSA, g, l15, sx, 0);
        smpv_tile<false>(bPV, Pl[w], accSB, accO, m_r, l_r, g, l15, sx, 0);
        ROT();
        SYNC();
        STAGE(t0 + 2, bST);
        qk_tile<false>(bQK, aq, accSB, g, l15, sx, 0);
        smpv_tile<false>(bPV, Pl[w], accSA, accO, m_r, l_r, g, l15, sx, 0);
        ROT();
    }

    // ---- masked pair (tiles nt-2 -> A, nt-1 -> B), only for qt >= 1
    if (qt >= 1) {
        SYNC();
        STAGE(nt - 1, bST);
        qk_tile<true >(bQK, aq, accSA, g, l15, sx, dqw - (nt - 2) * 64);
        smpv_tile<false>(bPV, Pl[w], accSB, accO, m_r, l_r, g, l15, sx, 0);
        ROT();
        SYNC();
        qk_tile<true >(bQK, aq, accSB, g, l15, sx, dqw - (nt - 1) * 64);
        smpv_tile<true >(bPV, Pl[w], accSA, accO, m_r, l_r, g, l15, sx, dqw - (nt - 2) * 64);
        ROT();
    }

    // ---- epilogue window: SM+PV(nt-1) from B (V tile resident, Pl wave-local)
    smpv_tile<true>(bPV, Pl[w], accSB, accO, m_r, l_r, g, l15, sx, dqw - (nt - 1) * 64);

    // epilogue: finish deferred row-sum (once per kernel), store O
    float l = l_r;
    l += __shfl_xor(l, 16);
    l += __shfl_xor(l, 32);
    const float inv = 1.0f / l;
    float* orow = O + ((size_t)bh * S_ + qbase + w * 16 + l15) * D_;
    #pragma unroll
    for (int d = 0; d < 4; ++d) {
        f32x4 o = accO[d] * inv;
        *(f32x4*)&orow[d * 16 + g * 4] = o;
    }
}

extern "C" void kernel_launch(void* const* d_in, const int* in_sizes, int n_in,
                              void* d_out, int out_size, void* d_ws, size_t ws_size,
                              hipStream_t stream) {
    const float* q = (const float*)d_in[0];
    const float* k = (const float*)d_in[1];
    const float* v = (const float*)d_in[2];
    // d_in[3] (mask) intentionally never read — causality computed in-kernel
    float* o = (float*)d_out;
    char* ws = (char*)d_ws;

    if (ws_size < WS_NEED) return;

    const int kblocks = (B_ * H_ * S_ * 8) / 256;        // 1024
    const int vblocks = B_ * H_ * (S_ / 64);             // 1024
    prep_kv<<<kblocks + vblocks, 256, 0, stream>>>(k, v, ws);
    attn_main<<<(S_ / BQ) * B_ * H_, 512, 0, stream>>>(q, ws, o);
}

// Round 18
// 48.015 us; speedup vs baseline: 1.0628x; 1.0628x over previous
//
#include <hip/hip_runtime.h>

#define B_   2
#define H_   16
#define S_   2048
#define D_   64
#define BQ   128    // q rows per block (16 per wave, 8 waves)
#define NW   8
// fold 1/sqrt(64) * log2(e) into Q so softmax works in exp2 domain
#define QSCALE 0.18033688011112042f
#define DEFER_THR 8.0f

typedef _Float16 f16x8 __attribute__((ext_vector_type(8)));
typedef float    f32x4 __attribute__((ext_vector_type(4)));

typedef const unsigned int __attribute__((address_space(1))) gu32;
typedef unsigned int       __attribute__((address_space(3))) lu32;

#define KBYTES_PER_HEAD (S_ * 128)                       // 256 KB f16 per head per tensor
#define WS_V_OFF ((size_t)B_ * H_ * KBYTES_PER_HEAD)     // 8.4 MB
#define WS_NEED  (2 * WS_V_OFF)

// ---------------- fused prepass (verified, unchanged): K -> swizzled f16 tiles,
// V -> transposed swizzled f16 tiles
__global__ __launch_bounds__(256) void prep_kv(const float* __restrict__ K,
                                               const float* __restrict__ V,
                                               char* __restrict__ ws)
{
    if (blockIdx.x < (B_ * H_ * S_ * 8) / 256) {
        const int gidx = blockIdx.x * 256 + threadIdx.x;
        const int gcol = gidx & 7;
        const int srow = gidx >> 3;                      // bh*S + s
        const float4* src = (const float4*)(K + (size_t)srow * D_ + gcol * 8);
        float4 a = src[0], b = src[1];
        f16x8 h;
        h[0] = (_Float16)a.x; h[1] = (_Float16)a.y; h[2] = (_Float16)a.z; h[3] = (_Float16)a.w;
        h[4] = (_Float16)b.x; h[5] = (_Float16)b.y; h[6] = (_Float16)b.z; h[7] = (_Float16)b.w;
        const int s  = srow & (S_ - 1);
        const int bh = srow >> 11;
        size_t off = (size_t)bh * KBYTES_PER_HEAD + (size_t)(s >> 6) * 8192
                   + (s & 63) * 128 + ((gcol ^ (s & 7)) << 4);
        *(f16x8*)(ws + off) = h;
    } else {
        __shared__ _Float16 Vl[64][72];
        const int tile = blockIdx.x - (B_ * H_ * S_ * 8) / 256;  // bh*32 + t
        const int bh = tile >> 5, t = tile & 31;
        const float* vb = V + ((size_t)bh * S_ + t * 64) * D_;
        const int tid = threadIdx.x;
        #pragma unroll
        for (int it = 0; it < 2; ++it) {
            const int row = (tid >> 3) + it * 32;
            const int c8  = (tid & 7) * 8;
            const float4* p = (const float4*)(vb + row * D_ + c8);
            float4 a = p[0], b = p[1];
            f16x8 h;
            h[0] = (_Float16)a.x; h[1] = (_Float16)a.y; h[2] = (_Float16)a.z; h[3] = (_Float16)a.w;
            h[4] = (_Float16)b.x; h[5] = (_Float16)b.y; h[6] = (_Float16)b.z; h[7] = (_Float16)b.w;
            *(f16x8*)&Vl[row][c8] = h;
        }
        __syncthreads();
        char* out = ws + WS_V_OFF + (size_t)bh * KBYTES_PER_HEAD + t * 8192;
        #pragma unroll
        for (int it = 0; it < 2; ++it) {
            const int task = tid + it * 256;
            const int d = task >> 3, kg = task & 7;
            f16x8 h;
            #pragma unroll
            for (int j = 0; j < 8; ++j) h[j] = Vl[kg * 8 + j][d];
            *(f16x8*)(out + d * 128 + ((kg ^ (d & 7)) << 4)) = h;
        }
    }
}

// ---------------- pipeline pieces ----------------
// QK^T swapped with PERMUTED output rows: sub MFMA 'sub' loads A-row i from K-row
//   kr(i) = 8*(i>>2) + (i&3) + 4*(sub&1) + 32*(sub>>1)
// so lane (l15,g) reg r of accS[sub] holds score for
//   k(sub,g,r) = 32*(sub>>1) + 8*g + 4*(sub&1) + r
// After exp2, lane-local chunks concat directly into PV's B-fragments:
//   pb0 = [sub0 | sub1]  (k = 8g..8g+7),  pb1 = [sub2 | sub3]  (k = 32+8g..32+8g+7)
// -> the P LDS roundtrip is eliminated.
template<bool MASK>
__device__ __forceinline__ void qk_tile(
    const _Float16* __restrict__ Kb, const f16x8 aq[2], f32x4 (&accS)[4],
    int g, int l15, int dq)
{
    const int rbase = 8 * (l15 >> 2) + (l15 & 3);
    #pragma unroll
    for (int s = 0; s < 4; ++s) accS[s] = (f32x4){0.f, 0.f, 0.f, 0.f};
    __builtin_amdgcn_s_setprio(1);
    #pragma unroll
    for (int sub = 0; sub < 4; ++sub) {
        // wave-uniform skip: min k of this sub = 32*(sub>>1) + 4*(sub&1)
        if (MASK && (32 * (sub >> 1) + 4 * (sub & 1) > dq + 15)) continue;
        const int kr  = rbase + 4 * (sub & 1) + 32 * (sub >> 1);
        const int sxk = (l15 & 3) + 4 * (sub & 1);       // = kr & 7 (swizzle key)
        #pragma unroll
        for (int kc = 0; kc < 2; ++kc) {
            f16x8 ak = *(const f16x8*)(Kb + (kr * 64 + (((kc * 4 + g) ^ sxk) << 3)));
            accS[sub] = __builtin_amdgcn_mfma_f32_16x16x32_f16(ak, aq[kc], accS[sub], 0, 0, 0);
        }
    }
    __builtin_amdgcn_s_setprio(0);
}

// online softmax (exp2 domain, defer-max) + PV, fully in-register P
template<bool MASK>
__device__ __forceinline__ void smpv_tile(
    const _Float16* __restrict__ SMb,
    f32x4 (&accS)[4], f32x4 accO[4], float& m_r, float& l_r,
    int g, int l15, int sx, int dq)
{
    const _Float16* Vb = SMb + 4096;

    auto msk = [&](int sub, int r) -> float {
        float s = accS[sub][r];
        if (MASK) {
            const int kk = 32 * (sub >> 1) + 8 * g + 4 * (sub & 1) + r;
            if (kk > dq + l15) s = -1e30f;
        }
        return s;
    };

    float pmax = -1e30f;
    #pragma unroll
    for (int sub = 0; sub < 4; ++sub)
        #pragma unroll
        for (int r = 0; r < 4; ++r) pmax = fmaxf(pmax, msk(sub, r));

    // defer-max (T13): wave-uniform ballot; common case no cross-lane ops
    if (!__all(pmax <= m_r + DEFER_THR)) {
        float mx = pmax;
        mx = fmaxf(mx, __shfl_xor(mx, 16));
        mx = fmaxf(mx, __shfl_xor(mx, 32));
        const float mnew  = fmaxf(m_r, mx);
        const float alpha = __builtin_amdgcn_exp2f(m_r - mnew);
        l_r *= alpha;
        #pragma unroll
        for (int d = 0; d < 4; ++d)
            #pragma unroll
            for (int r = 0; r < 4; ++r) accO[d][r] *= alpha;
        m_r = mnew;
    }

    // exp2 with (stale-by-<=THR) m_r, packed straight into PV B-fragments
    float rs = 0.f;
    f16x8 pb0, pb1;
    #pragma unroll
    for (int sub = 0; sub < 4; ++sub) {
        float p0 = __builtin_amdgcn_exp2f(msk(sub, 0) - m_r);
        float p1 = __builtin_amdgcn_exp2f(msk(sub, 1) - m_r);
        float p2 = __builtin_amdgcn_exp2f(msk(sub, 2) - m_r);
        float p3 = __builtin_amdgcn_exp2f(msk(sub, 3) - m_r);
        rs += (p0 + p1) + (p2 + p3);
        if (sub == 0) {
            pb0[0] = (_Float16)p0; pb0[1] = (_Float16)p1;
            pb0[2] = (_Float16)p2; pb0[3] = (_Float16)p3;
        } else if (sub == 1) {
            pb0[4] = (_Float16)p0; pb0[5] = (_Float16)p1;
            pb0[6] = (_Float16)p2; pb0[7] = (_Float16)p3;
        } else if (sub == 2) {
            pb1[0] = (_Float16)p0; pb1[1] = (_Float16)p1;
            pb1[2] = (_Float16)p2; pb1[3] = (_Float16)p3;
        } else {
            pb1[4] = (_Float16)p0; pb1[5] = (_Float16)p1;
            pb1[6] = (_Float16)p2; pb1[7] = (_Float16)p3;
        }
    }
    l_r += rs;

    // PV swapped: A = V^T rows (d), B = P^T -> accO[dsub]: d = dsub*16+4g+r, q = l15
    __builtin_amdgcn_s_setprio(1);
    #pragma unroll
    for (int d = 0; d < 4; ++d) {
        f16x8 av0 = *(const f16x8*)(Vb + ((d * 16 + l15) * 64 + (((0 * 4 + g) ^ sx) << 3)));
        accO[d] = __builtin_amdgcn_mfma_f32_16x16x32_f16(av0, pb0, accO[d], 0, 0, 0);
        f16x8 av1 = *(const f16x8*)(Vb + ((d * 16 + l15) * 64 + (((1 * 4 + g) ^ sx) << 3)));
        accO[d] = __builtin_amdgcn_mfma_f32_16x16x32_f16(av1, pb1, accO[d], 0, 0, 0);
    }
    __builtin_amdgcn_s_setprio(0);
}

__global__ __launch_bounds__(512, 4) void attn_main(
    const float* __restrict__ Q, const char* __restrict__ ws, float* __restrict__ O)
{
    __shared__ _Float16 SM[3][8192];        // triple buffer: [ K 0..4095 | V 4096..8191 ]

    const int tid  = threadIdx.x;
    const int lane = tid & 63;
    const int w    = tid >> 6;              // wave 0..7
    const int g    = lane >> 4;
    const int l15  = lane & 15;
    const int sx   = l15 & 7;

    // Balanced heavy+light strip pairing with head->XCD affinity (id%8 = bh%8)
    const int id    = blockIdx.x;
    const int bh    = id & 31;
    const int qi    = id >> 5;              // 0..15
    const int qt    = (id < 256) ? (15 - qi) : (qi - 8);
    const int qbase = qt * BQ;

    const char* kbase = ws + (size_t)bh * KBYTES_PER_HEAD;
    const char* vbase = ws + WS_V_OFF + (size_t)bh * KBYTES_PER_HEAD;

    // hoist Q fragments, pre-scaled into exp2 domain
    f16x8 aq[2];
    {
        const float* qrow = Q + ((size_t)bh * S_ + qbase + w * 16 + l15) * D_;
        #pragma unroll
        for (int kc = 0; kc < 2; ++kc) {
            const float4* p = (const float4*)(qrow + kc * 32 + g * 8);
            float4 x0 = p[0], x1 = p[1];
            f16x8 h;
            h[0] = (_Float16)(x0.x * QSCALE); h[1] = (_Float16)(x0.y * QSCALE);
            h[2] = (_Float16)(x0.z * QSCALE); h[3] = (_Float16)(x0.w * QSCALE);
            h[4] = (_Float16)(x1.x * QSCALE); h[5] = (_Float16)(x1.y * QSCALE);
            h[6] = (_Float16)(x1.z * QSCALE); h[7] = (_Float16)(x1.w * QSCALE);
            aq[kc] = h;
        }
    }

    f32x4 accO[4];
    #pragma unroll
    for (int i = 0; i < 4; ++i) accO[i] = (f32x4){0.f, 0.f, 0.f, 0.f};
    float m_r = -1e30f, l_r = 0.f;
    f32x4 accSA[4], accSB[4];

    const int nt  = 2 * qt + 2;             // 64-wide tiles; last two straddle the diagonal
    const int dqw = qbase + w * 16;         // wave q-row base

    // rotating buffer pointers: bQK = tile t, bPV = tile t-1, bST = stage target (t+1)
    _Float16* bQK = &SM[0][0];
    _Float16* bST = &SM[1][0];
    _Float16* bPV = &SM[2][0];

    // stage tile t into dst: 16 x 1KB chunks, 2 per wave (pre-swizzled source, linear dest)
    auto STAGE = [&](int t, _Float16* dst) {
        #pragma unroll
        for (int i = 0; i < 2; ++i) {
            const int c = w * 2 + i;
            const char* src = (c < 8 ? kbase + (size_t)t * 8192 + c * 1024
                                     : vbase + (size_t)t * 8192 + (c - 8) * 1024) + lane * 16;
            __builtin_amdgcn_global_load_lds((gu32*)src, (lu32*)(dst + c * 512), 16, 0, 0);
        }
    };
    auto SYNC = []() {
        asm volatile("s_waitcnt vmcnt(0)" ::: "memory");
        __builtin_amdgcn_s_barrier();
    };
    auto ROT = [&]() { _Float16* tmp = bPV; bPV = bQK; bQK = bST; bST = tmp; };

    STAGE(0, bQK);

    // ---- window 0: QK(0) -> A
    SYNC();
    STAGE(1, bST);
    if (qt == 0) qk_tile<true >(bQK, aq, accSA, g, l15, dqw);
    else         qk_tile<false>(bQK, aq, accSA, g, l15, 0);
    ROT();

    // ---- window 1: QK(1) -> B, SM+PV(0) from A
    SYNC();
    if (nt > 2) STAGE(2, bST);
    if (qt == 0) {
        qk_tile<true >(bQK, aq, accSB, g, l15, dqw - 64);
        smpv_tile<true >(bPV, accSA, accO, m_r, l_r, g, l15, sx, dqw);
    } else {
        qk_tile<false>(bQK, aq, accSB, g, l15, 0);
        smpv_tile<false>(bPV, accSA, accO, m_r, l_r, g, l15, sx, 0);
    }
    ROT();

    // ---- steady windows: tiles 2i (->A) and 2i+1 (->B), all unmasked
    for (int i = 1; i < qt; ++i) {
        const int t0 = 2 * i;
        SYNC();
        STAGE(t0 + 1, bST);
        qk_tile<false>(bQK, aq, accSA, g, l15, 0);
        smpv_tile<false>(bPV, accSB, accO, m_r, l_r, g, l15, sx, 0);
        ROT();
        SYNC();
        STAGE(t0 + 2, bST);
        qk_tile<false>(bQK, aq, accSB, g, l15, 0);
        smpv_tile<false>(bPV, accSA, accO, m_r, l_r, g, l15, sx, 0);
        ROT();
    }

    // ---- masked pair (tiles nt-2 -> A, nt-1 -> B), only for qt >= 1
    if (qt >= 1) {
        SYNC();
        STAGE(nt - 1, bST);
        qk_tile<true >(bQK, aq, accSA, g, l15, dqw - (nt - 2) * 64);
        smpv_tile<false>(bPV, accSB, accO, m_r, l_r, g, l15, sx, 0);
        ROT();
        SYNC();
        qk_tile<true >(bQK, aq, accSB, g, l15, dqw - (nt - 1) * 64);
        smpv_tile<true >(bPV, accSA, accO, m_r, l_r, g, l15, sx, dqw - (nt - 2) * 64);
        ROT();
    }

    // ---- epilogue window: SM+PV(nt-1) from B (V tile resident)
    smpv_tile<true>(bPV, accSB, accO, m_r, l_r, g, l15, sx, dqw - (nt - 1) * 64);

    // epilogue: finish deferred row-sum (once per kernel), store O
    float l = l_r;
    l += __shfl_xor(l, 16);
    l += __shfl_xor(l, 32);
    const float inv = 1.0f / l;
    float* orow = O + ((size_t)bh * S_ + qbase + w * 16 + l15) * D_;
    #pragma unroll
    for (int d = 0; d < 4; ++d) {
        f32x4 o = accO[d] * inv;
        *(f32x4*)&orow[d * 16 + g * 4] = o;
    }
}

extern "C" void kernel_launch(void* const* d_in, const int* in_sizes, int n_in,
                              void* d_out, int out_size, void* d_ws, size_t ws_size,
                              hipStream_t stream) {
    const float* q = (const float*)d_in[0];
    const float* k = (const float*)d_in[1];
    const float* v = (const float*)d_in[2];
    // d_in[3] (mask) intentionally never read — causality computed in-kernel
    float* o = (float*)d_out;
    char* ws = (char*)d_ws;

    if (ws_size < WS_NEED) return;

    const int kblocks = (B_ * H_ * S_ * 8) / 256;        // 1024
    const int vblocks = B_ * H_ * (S_ / 64);             // 1024
    prep_kv<<<kblocks + vblocks, 256, 0, stream>>>(k, v, ws);
    attn_main<<<(S_ / BQ) * B_ * H_, 512, 0, stream>>>(q, ws, o);
}

// Round 19
// 44.855 us; speedup vs baseline: 1.1377x; 1.0704x over previous
//
#include <hip/hip_runtime.h>

#define B_   2
#define H_   16
#define S_   2048
#define D_   64
#define BQ   128    // q rows per block (16 per wave, 8 waves)
#define NW   8
// fold 1/sqrt(64) * log2(e) into Q so softmax works in exp2 domain
#define QSCALE 0.18033688011112042f
#define DEFER_THR 8.0f

typedef _Float16 f16x8 __attribute__((ext_vector_type(8)));
typedef float    f32x4 __attribute__((ext_vector_type(4)));

typedef const unsigned int __attribute__((address_space(1))) gu32;
typedef unsigned int       __attribute__((address_space(3))) lu32;

#define KBYTES_PER_HEAD (S_ * 128)                       // 256 KB f16 per head per tensor
#define WS_V_OFF ((size_t)B_ * H_ * KBYTES_PER_HEAD)     // 8.4 MB
#define WS_NEED  (2 * WS_V_OFF)

// ---------------- fused prepass (verified, unchanged): K -> swizzled f16 tiles,
// V -> transposed swizzled f16 tiles
__global__ __launch_bounds__(256) void prep_kv(const float* __restrict__ K,
                                               const float* __restrict__ V,
                                               char* __restrict__ ws)
{
    if (blockIdx.x < (B_ * H_ * S_ * 8) / 256) {
        const int gidx = blockIdx.x * 256 + threadIdx.x;
        const int gcol = gidx & 7;
        const int srow = gidx >> 3;                      // bh*S + s
        const float4* src = (const float4*)(K + (size_t)srow * D_ + gcol * 8);
        float4 a = src[0], b = src[1];
        f16x8 h;
        h[0] = (_Float16)a.x; h[1] = (_Float16)a.y; h[2] = (_Float16)a.z; h[3] = (_Float16)a.w;
        h[4] = (_Float16)b.x; h[5] = (_Float16)b.y; h[6] = (_Float16)b.z; h[7] = (_Float16)b.w;
        const int s  = srow & (S_ - 1);
        const int bh = srow >> 11;
        size_t off = (size_t)bh * KBYTES_PER_HEAD + (size_t)(s >> 6) * 8192
                   + (s & 63) * 128 + ((gcol ^ (s & 7)) << 4);
        *(f16x8*)(ws + off) = h;
    } else {
        __shared__ _Float16 Vl[64][72];
        const int tile = blockIdx.x - (B_ * H_ * S_ * 8) / 256;  // bh*32 + t
        const int bh = tile >> 5, t = tile & 31;
        const float* vb = V + ((size_t)bh * S_ + t * 64) * D_;
        const int tid = threadIdx.x;
        #pragma unroll
        for (int it = 0; it < 2; ++it) {
            const int row = (tid >> 3) + it * 32;
            const int c8  = (tid & 7) * 8;
            const float4* p = (const float4*)(vb + row * D_ + c8);
            float4 a = p[0], b = p[1];
            f16x8 h;
            h[0] = (_Float16)a.x; h[1] = (_Float16)a.y; h[2] = (_Float16)a.z; h[3] = (_Float16)a.w;
            h[4] = (_Float16)b.x; h[5] = (_Float16)b.y; h[6] = (_Float16)b.z; h[7] = (_Float16)b.w;
            *(f16x8*)&Vl[row][c8] = h;
        }
        __syncthreads();
        char* out = ws + WS_V_OFF + (size_t)bh * KBYTES_PER_HEAD + t * 8192;
        #pragma unroll
        for (int it = 0; it < 2; ++it) {
            const int task = tid + it * 256;
            const int d = task >> 3, kg = task & 7;
            f16x8 h;
            #pragma unroll
            for (int j = 0; j < 8; ++j) h[j] = Vl[kg * 8 + j][d];
            *(f16x8*)(out + d * 128 + ((kg ^ (d & 7)) << 4)) = h;
        }
    }
}

// ---------------- pipeline pieces (identical math/layouts to verified R18) ----------------
// QK^T swapped with PERMUTED output rows: sub MFMA 'sub' loads A-row i from K-row
//   kr(i) = 8*(i>>2) + (i&3) + 4*(sub&1) + 32*(sub>>1)
// so lane (l15,g) reg r of accS[sub] holds score k = 32*(sub>>1) + 8*g + 4*(sub&1) + r;
// after exp2, lane-local chunks concat directly into PV's B-fragments (no P LDS roundtrip).
template<bool MASK>
__device__ __forceinline__ void qk_tile(
    const _Float16* __restrict__ Kb, const f16x8 aq[2], f32x4 (&accS)[4],
    int g, int l15, int dq)
{
    const int rbase = 8 * (l15 >> 2) + (l15 & 3);
    #pragma unroll
    for (int s = 0; s < 4; ++s) accS[s] = (f32x4){0.f, 0.f, 0.f, 0.f};
    __builtin_amdgcn_s_setprio(1);
    #pragma unroll
    for (int sub = 0; sub < 4; ++sub) {
        // wave-uniform skip: min k of this sub = 32*(sub>>1) + 4*(sub&1)
        if (MASK && (32 * (sub >> 1) + 4 * (sub & 1) > dq + 15)) continue;
        const int kr  = rbase + 4 * (sub & 1) + 32 * (sub >> 1);
        const int sxk = (l15 & 3) + 4 * (sub & 1);       // = kr & 7 (swizzle key)
        #pragma unroll
        for (int kc = 0; kc < 2; ++kc) {
            f16x8 ak = *(const f16x8*)(Kb + (kr * 64 + (((kc * 4 + g) ^ sxk) << 3)));
            accS[sub] = __builtin_amdgcn_mfma_f32_16x16x32_f16(ak, aq[kc], accS[sub], 0, 0, 0);
        }
    }
    __builtin_amdgcn_s_setprio(0);
}

// online softmax (exp2 domain, defer-max) + PV, fully in-register P
template<bool MASK>
__device__ __forceinline__ void smpv_tile(
    const _Float16* __restrict__ Vb,
    f32x4 (&accS)[4], f32x4 accO[4], float& m_r, float& l_r,
    int g, int l15, int sx, int dq)
{
    auto msk = [&](int sub, int r) -> float {
        float s = accS[sub][r];
        if (MASK) {
            const int kk = 32 * (sub >> 1) + 8 * g + 4 * (sub & 1) + r;
            if (kk > dq + l15) s = -1e30f;
        }
        return s;
    };

    float pmax = -1e30f;
    #pragma unroll
    for (int sub = 0; sub < 4; ++sub)
        #pragma unroll
        for (int r = 0; r < 4; ++r) pmax = fmaxf(pmax, msk(sub, r));

    // defer-max (T13): wave-uniform ballot; common case no cross-lane ops
    if (!__all(pmax <= m_r + DEFER_THR)) {
        float mx = pmax;
        mx = fmaxf(mx, __shfl_xor(mx, 16));
        mx = fmaxf(mx, __shfl_xor(mx, 32));
        const float mnew  = fmaxf(m_r, mx);
        const float alpha = __builtin_amdgcn_exp2f(m_r - mnew);
        l_r *= alpha;
        #pragma unroll
        for (int d = 0; d < 4; ++d)
            #pragma unroll
            for (int r = 0; r < 4; ++r) accO[d][r] *= alpha;
        m_r = mnew;
    }

    // exp2 with (stale-by-<=THR) m_r, packed straight into PV B-fragments
    float rs = 0.f;
    f16x8 pb0, pb1;
    #pragma unroll
    for (int sub = 0; sub < 4; ++sub) {
        float p0 = __builtin_amdgcn_exp2f(msk(sub, 0) - m_r);
        float p1 = __builtin_amdgcn_exp2f(msk(sub, 1) - m_r);
        float p2 = __builtin_amdgcn_exp2f(msk(sub, 2) - m_r);
        float p3 = __builtin_amdgcn_exp2f(msk(sub, 3) - m_r);
        rs += (p0 + p1) + (p2 + p3);
        if (sub == 0) {
            pb0[0] = (_Float16)p0; pb0[1] = (_Float16)p1;
            pb0[2] = (_Float16)p2; pb0[3] = (_Float16)p3;
        } else if (sub == 1) {
            pb0[4] = (_Float16)p0; pb0[5] = (_Float16)p1;
            pb0[6] = (_Float16)p2; pb0[7] = (_Float16)p3;
        } else if (sub == 2) {
            pb1[0] = (_Float16)p0; pb1[1] = (_Float16)p1;
            pb1[2] = (_Float16)p2; pb1[3] = (_Float16)p3;
        } else {
            pb1[4] = (_Float16)p0; pb1[5] = (_Float16)p1;
            pb1[6] = (_Float16)p2; pb1[7] = (_Float16)p3;
        }
    }
    l_r += rs;

    // PV swapped: A = V^T rows (d), B = P^T -> accO[dsub]: d = dsub*16+4g+r, q = l15
    __builtin_amdgcn_s_setprio(1);
    #pragma unroll
    for (int d = 0; d < 4; ++d) {
        f16x8 av0 = *(const f16x8*)(Vb + ((d * 16 + l15) * 64 + (((0 * 4 + g) ^ sx) << 3)));
        accO[d] = __builtin_amdgcn_mfma_f32_16x16x32_f16(av0, pb0, accO[d], 0, 0, 0);
        f16x8 av1 = *(const f16x8*)(Vb + ((d * 16 + l15) * 64 + (((1 * 4 + g) ^ sx) << 3)));
        accO[d] = __builtin_amdgcn_mfma_f32_16x16x32_f16(av1, pb1, accO[d], 0, 0, 0);
    }
    __builtin_amdgcn_s_setprio(0);
}

__global__ __launch_bounds__(512, 4) void attn_main(
    const float* __restrict__ Q, const char* __restrict__ ws, float* __restrict__ O)
{
    // Asymmetric buffer pools: K needs 4 tiles live per pair, V needs 5 (smpv lags
    // one window). 72 KB/block -> 2 blocks/CU, 16 waves (same occupancy as R18).
    __shared__ _Float16 KBuf[4][4096];
    __shared__ _Float16 VBuf[5][4096];

    const int tid  = threadIdx.x;
    const int lane = tid & 63;
    const int w    = tid >> 6;              // wave 0..7
    const int g    = lane >> 4;
    const int l15  = lane & 15;
    const int sx   = l15 & 7;

    // Balanced heavy+light strip pairing with head->XCD affinity (id%8 = bh%8)
    const int id    = blockIdx.x;
    const int bh    = id & 31;
    const int qi    = id >> 5;              // 0..15
    const int qt    = (id < 256) ? (15 - qi) : (qi - 8);
    const int qbase = qt * BQ;

    const char* kbase = ws + (size_t)bh * KBYTES_PER_HEAD;
    const char* vbase = ws + WS_V_OFF + (size_t)bh * KBYTES_PER_HEAD;

    // hoist Q fragments, pre-scaled into exp2 domain
    f16x8 aq[2];
    {
        const float* qrow = Q + ((size_t)bh * S_ + qbase + w * 16 + l15) * D_;
        #pragma unroll
        for (int kc = 0; kc < 2; ++kc) {
            const float4* p = (const float4*)(qrow + kc * 32 + g * 8);
            float4 x0 = p[0], x1 = p[1];
            f16x8 h;
            h[0] = (_Float16)(x0.x * QSCALE); h[1] = (_Float16)(x0.y * QSCALE);
            h[2] = (_Float16)(x0.z * QSCALE); h[3] = (_Float16)(x0.w * QSCALE);
            h[4] = (_Float16)(x1.x * QSCALE); h[5] = (_Float16)(x1.y * QSCALE);
            h[6] = (_Float16)(x1.z * QSCALE); h[7] = (_Float16)(x1.w * QSCALE);
            aq[kc] = h;
        }
    }

    f32x4 accO[4];
    #pragma unroll
    for (int i = 0; i < 4; ++i) accO[i] = (f32x4){0.f, 0.f, 0.f, 0.f};
    float m_r = -1e30f, l_r = 0.f;
    f32x4 accSA[4], accSB[4];

    const int nt  = 2 * qt + 2;             // 64-wide tiles; last two straddle the diagonal
    const int dqw = qbase + w * 16;         // wave q-row base
    const int dqA = dqw - (nt - 2) * 64;    // diag offsets of the masked pair
    const int dqB = dqw - (nt - 1) * 64;

    // rotating pools. Pair i: K(2i)=kb0 K(2i+1)=kb1, stage K(2i+2)->kb2 K(2i+3)->kb3;
    //                 V(2i-1)=vb0 V(2i)=vb1 V(2i+1)=vb2, stage V(2i+2)->vb3 V(2i+3)->vb4.
    _Float16 *kb0 = &KBuf[0][0], *kb1 = &KBuf[1][0], *kb2 = &KBuf[2][0], *kb3 = &KBuf[3][0];
    _Float16 *vb0 = &VBuf[0][0], *vb1 = &VBuf[1][0], *vb2 = &VBuf[2][0],
             *vb3 = &VBuf[3][0], *vb4 = &VBuf[4][0];

    auto STAGE_K = [&](int t, _Float16* dst) {
        const char* src = kbase + (size_t)t * 8192 + w * 1024 + lane * 16;
        __builtin_amdgcn_global_load_lds((gu32*)src, (lu32*)(dst + w * 512), 16, 0, 0);
    };
    auto STAGE_V = [&](int t, _Float16* dst) {
        const char* src = vbase + (size_t)t * 8192 + w * 1024 + lane * 16;
        __builtin_amdgcn_global_load_lds((gu32*)src, (lu32*)(dst + w * 512), 16, 0, 0);
    };
    auto SYNC = []() {
        asm volatile("s_waitcnt vmcnt(0)" ::: "memory");
        __builtin_amdgcn_s_barrier();
    };
    auto ROT = [&]() {
        _Float16* t0 = kb0; _Float16* t1 = kb1;
        kb0 = kb2; kb1 = kb3; kb2 = t0; kb3 = t1;
        _Float16* u0 = vb0; _Float16* u1 = vb1;
        vb0 = vb2; vb1 = vb3; vb2 = vb4; vb3 = u0; vb4 = u1;
    };

    // prologue: stage tiles 0,1 (V(0)->vb1, V(1)->vb2 per pair-0 expectations)
    STAGE_K(0, kb0); STAGE_V(0, vb1);
    STAGE_K(1, kb1); STAGE_V(1, vb2);

    // ---- unmasked pairs: windows (2i, 2i+1), i = 0..qt-1 — ONE barrier per pair
    for (int i = 0; i < qt; ++i) {
        SYNC();                              // stages of 2i, 2i+1 complete; pool slots free
        STAGE_K(2 * i + 2, kb2); STAGE_V(2 * i + 2, vb3);
        STAGE_K(2 * i + 3, kb3); STAGE_V(2 * i + 3, vb4);
        qk_tile<false>(kb0, aq, accSA, g, l15, 0);
        if (i > 0) smpv_tile<false>(vb0, accSB, accO, m_r, l_r, g, l15, sx, 0);
        qk_tile<false>(kb1, aq, accSB, g, l15, 0);
        smpv_tile<false>(vb1, accSA, accO, m_r, l_r, g, l15, sx, 0);
        ROT();
    }

    // ---- masked pair (tiles nt-2, nt-1)
    SYNC();
    qk_tile<true>(kb0, aq, accSA, g, l15, dqA);
    if (qt > 0) smpv_tile<false>(vb0, accSB, accO, m_r, l_r, g, l15, sx, 0);
    qk_tile<true>(kb1, aq, accSB, g, l15, dqB);
    smpv_tile<true>(vb1, accSA, accO, m_r, l_r, g, l15, sx, dqA);
    ROT();
    // epilogue window: SM+PV(nt-1); V(nt-1) sits at vb0 after rotation
    smpv_tile<true>(vb0, accSB, accO, m_r, l_r, g, l15, sx, dqB);

    // epilogue: finish deferred row-sum (once per kernel), store O
    float l = l_r;
    l += __shfl_xor(l, 16);
    l += __shfl_xor(l, 32);
    const float inv = 1.0f / l;
    float* orow = O + ((size_t)bh * S_ + qbase + w * 16 + l15) * D_;
    #pragma unroll
    for (int d = 0; d < 4; ++d) {
        f32x4 o = accO[d] * inv;
        *(f32x4*)&orow[d * 16 + g * 4] = o;
    }
}

extern "C" void kernel_launch(void* const* d_in, const int* in_sizes, int n_in,
                              void* d_out, int out_size, void* d_ws, size_t ws_size,
                              hipStream_t stream) {
    const float* q = (const float*)d_in[0];
    const float* k = (const float*)d_in[1];
    const float* v = (const float*)d_in[2];
    // d_in[3] (mask) intentionally never read — causality computed in-kernel
    float* o = (float*)d_out;
    char* ws = (char*)d_ws;

    if (ws_size < WS_NEED) return;

    const int kblocks = (B_ * H_ * S_ * 8) / 256;        // 1024
    const int vblocks = B_ * H_ * (S_ / 64);             // 1024
    prep_kv<<<kblocks + vblocks, 256, 0, stream>>>(k, v, ws);
    attn_main<<<(S_ / BQ) * B_ * H_, 512, 0, stream>>>(q, ws, o);
}

// Round 20
// 44.851 us; speedup vs baseline: 1.1378x; 1.0001x over previous
//
#include <hip/hip_runtime.h>

#define B_   2
#define H_   16
#define S_   2048
#define D_   64
#define BQ   128    // q rows per block (16 per wave, 8 waves)
#define NW   8
// fold 1/sqrt(64) * log2(e) into Q so softmax works in exp2 domain
#define QSCALE 0.18033688011112042f
#define DEFER_THR 8.0f

typedef _Float16 f16x8 __attribute__((ext_vector_type(8)));
typedef float    f32x4 __attribute__((ext_vector_type(4)));

typedef const unsigned int __attribute__((address_space(1))) gu32;
typedef unsigned int       __attribute__((address_space(3))) lu32;

#define KBYTES_PER_HEAD (S_ * 128)                       // 256 KB f16 per head per tensor
#define WS_V_OFF ((size_t)B_ * H_ * KBYTES_PER_HEAD)     // 8.4 MB
#define WS_NEED  (2 * WS_V_OFF)

// ---------------- fused prepass (verified, unchanged): K -> swizzled f16 tiles,
// V -> transposed swizzled f16 tiles
__global__ __launch_bounds__(256) void prep_kv(const float* __restrict__ K,
                                               const float* __restrict__ V,
                                               char* __restrict__ ws)
{
    if (blockIdx.x < (B_ * H_ * S_ * 8) / 256) {
        const int gidx = blockIdx.x * 256 + threadIdx.x;
        const int gcol = gidx & 7;
        const int srow = gidx >> 3;                      // bh*S + s
        const float4* src = (const float4*)(K + (size_t)srow * D_ + gcol * 8);
        float4 a = src[0], b = src[1];
        f16x8 h;
        h[0] = (_Float16)a.x; h[1] = (_Float16)a.y; h[2] = (_Float16)a.z; h[3] = (_Float16)a.w;
        h[4] = (_Float16)b.x; h[5] = (_Float16)b.y; h[6] = (_Float16)b.z; h[7] = (_Float16)b.w;
        const int s  = srow & (S_ - 1);
        const int bh = srow >> 11;
        size_t off = (size_t)bh * KBYTES_PER_HEAD + (size_t)(s >> 6) * 8192
                   + (s & 63) * 128 + ((gcol ^ (s & 7)) << 4);
        *(f16x8*)(ws + off) = h;
    } else {
        __shared__ _Float16 Vl[64][72];
        const int tile = blockIdx.x - (B_ * H_ * S_ * 8) / 256;  // bh*32 + t
        const int bh = tile >> 5, t = tile & 31;
        const float* vb = V + ((size_t)bh * S_ + t * 64) * D_;
        const int tid = threadIdx.x;
        #pragma unroll
        for (int it = 0; it < 2; ++it) {
            const int row = (tid >> 3) + it * 32;
            const int c8  = (tid & 7) * 8;
            const float4* p = (const float4*)(vb + row * D_ + c8);
            float4 a = p[0], b = p[1];
            f16x8 h;
            h[0] = (_Float16)a.x; h[1] = (_Float16)a.y; h[2] = (_Float16)a.z; h[3] = (_Float16)a.w;
            h[4] = (_Float16)b.x; h[5] = (_Float16)b.y; h[6] = (_Float16)b.z; h[7] = (_Float16)b.w;
            *(f16x8*)&Vl[row][c8] = h;
        }
        __syncthreads();
        char* out = ws + WS_V_OFF + (size_t)bh * KBYTES_PER_HEAD + t * 8192;
        #pragma unroll
        for (int it = 0; it < 2; ++it) {
            const int task = tid + it * 256;
            const int d = task >> 3, kg = task & 7;
            f16x8 h;
            #pragma unroll
            for (int j = 0; j < 8; ++j) h[j] = Vl[kg * 8 + j][d];
            *(f16x8*)(out + d * 128 + ((kg ^ (d & 7)) << 4)) = h;
        }
    }
}

// ---------------- pipeline pieces (identical math/layouts to verified R18) ----------------
// QK^T swapped with PERMUTED output rows: sub MFMA 'sub' loads A-row i from K-row
//   kr(i) = 8*(i>>2) + (i&3) + 4*(sub&1) + 32*(sub>>1)
// so lane (l15,g) reg r of accS[sub] holds score k = 32*(sub>>1) + 8*g + 4*(sub&1) + r;
// after exp2, lane-local chunks concat directly into PV's B-fragments (no P LDS roundtrip).
template<bool MASK>
__device__ __forceinline__ void qk_tile(
    const _Float16* __restrict__ Kb, const f16x8 aq[2], f32x4 (&accS)[4],
    int g, int l15, int dq)
{
    const int rbase = 8 * (l15 >> 2) + (l15 & 3);
    #pragma unroll
    for (int s = 0; s < 4; ++s) accS[s] = (f32x4){0.f, 0.f, 0.f, 0.f};
    __builtin_amdgcn_s_setprio(1);
    #pragma unroll
    for (int sub = 0; sub < 4; ++sub) {
        // wave-uniform skip: min k of this sub = 32*(sub>>1) + 4*(sub&1)
        if (MASK && (32 * (sub >> 1) + 4 * (sub & 1) > dq + 15)) continue;
        const int kr  = rbase + 4 * (sub & 1) + 32 * (sub >> 1);
        const int sxk = (l15 & 3) + 4 * (sub & 1);       // = kr & 7 (swizzle key)
        #pragma unroll
        for (int kc = 0; kc < 2; ++kc) {
            f16x8 ak = *(const f16x8*)(Kb + (kr * 64 + (((kc * 4 + g) ^ sxk) << 3)));
            accS[sub] = __builtin_amdgcn_mfma_f32_16x16x32_f16(ak, aq[kc], accS[sub], 0, 0, 0);
        }
    }
    __builtin_amdgcn_s_setprio(0);
}

// online softmax (exp2 domain, defer-max) + PV, fully in-register P
template<bool MASK>
__device__ __forceinline__ void smpv_tile(
    const _Float16* __restrict__ Vb,
    f32x4 (&accS)[4], f32x4 accO[4], float& m_r, float& l_r,
    int g, int l15, int sx, int dq)
{
    auto msk = [&](int sub, int r) -> float {
        float s = accS[sub][r];
        if (MASK) {
            const int kk = 32 * (sub >> 1) + 8 * g + 4 * (sub & 1) + r;
            if (kk > dq + l15) s = -1e30f;
        }
        return s;
    };

    float pmax = -1e30f;
    #pragma unroll
    for (int sub = 0; sub < 4; ++sub)
        #pragma unroll
        for (int r = 0; r < 4; ++r) pmax = fmaxf(pmax, msk(sub, r));

    // defer-max (T13): wave-uniform ballot; common case no cross-lane ops
    if (!__all(pmax <= m_r + DEFER_THR)) {
        float mx = pmax;
        mx = fmaxf(mx, __shfl_xor(mx, 16));
        mx = fmaxf(mx, __shfl_xor(mx, 32));
        const float mnew  = fmaxf(m_r, mx);
        const float alpha = __builtin_amdgcn_exp2f(m_r - mnew);
        l_r *= alpha;
        #pragma unroll
        for (int d = 0; d < 4; ++d)
            #pragma unroll
            for (int r = 0; r < 4; ++r) accO[d][r] *= alpha;
        m_r = mnew;
    }

    // exp2 with (stale-by-<=THR) m_r, packed straight into PV B-fragments
    float rs = 0.f;
    f16x8 pb0, pb1;
    #pragma unroll
    for (int sub = 0; sub < 4; ++sub) {
        float p0 = __builtin_amdgcn_exp2f(msk(sub, 0) - m_r);
        float p1 = __builtin_amdgcn_exp2f(msk(sub, 1) - m_r);
        float p2 = __builtin_amdgcn_exp2f(msk(sub, 2) - m_r);
        float p3 = __builtin_amdgcn_exp2f(msk(sub, 3) - m_r);
        rs += (p0 + p1) + (p2 + p3);
        if (sub == 0) {
            pb0[0] = (_Float16)p0; pb0[1] = (_Float16)p1;
            pb0[2] = (_Float16)p2; pb0[3] = (_Float16)p3;
        } else if (sub == 1) {
            pb0[4] = (_Float16)p0; pb0[5] = (_Float16)p1;
            pb0[6] = (_Float16)p2; pb0[7] = (_Float16)p3;
        } else if (sub == 2) {
            pb1[0] = (_Float16)p0; pb1[1] = (_Float16)p1;
            pb1[2] = (_Float16)p2; pb1[3] = (_Float16)p3;
        } else {
            pb1[4] = (_Float16)p0; pb1[5] = (_Float16)p1;
            pb1[6] = (_Float16)p2; pb1[7] = (_Float16)p3;
        }
    }
    l_r += rs;

    // PV swapped: A = V^T rows (d), B = P^T -> accO[dsub]: d = dsub*16+4g+r, q = l15
    __builtin_amdgcn_s_setprio(1);
    #pragma unroll
    for (int d = 0; d < 4; ++d) {
        f16x8 av0 = *(const f16x8*)(Vb + ((d * 16 + l15) * 64 + (((0 * 4 + g) ^ sx) << 3)));
        accO[d] = __builtin_amdgcn_mfma_f32_16x16x32_f16(av0, pb0, accO[d], 0, 0, 0);
        f16x8 av1 = *(const f16x8*)(Vb + ((d * 16 + l15) * 64 + (((1 * 4 + g) ^ sx) << 3)));
        accO[d] = __builtin_amdgcn_mfma_f32_16x16x32_f16(av1, pb1, accO[d], 0, 0, 0);
    }
    __builtin_amdgcn_s_setprio(0);
}

__global__ __launch_bounds__(512, 4) void attn_main(
    const float* __restrict__ Q, const char* __restrict__ ws, float* __restrict__ O)
{
    // Asymmetric buffer pools: K needs 4 tiles live per pair, V needs 5 (smpv lags
    // one window). 72 KB/block -> 2 blocks/CU, 16 waves (same occupancy as R18).
    __shared__ _Float16 KBuf[4][4096];
    __shared__ _Float16 VBuf[5][4096];

    const int tid  = threadIdx.x;
    const int lane = tid & 63;
    const int w    = tid >> 6;              // wave 0..7
    const int g    = lane >> 4;
    const int l15  = lane & 15;
    const int sx   = l15 & 7;

    // Balanced heavy+light strip pairing with head->XCD affinity (id%8 = bh%8)
    const int id    = blockIdx.x;
    const int bh    = id & 31;
    const int qi    = id >> 5;              // 0..15
    const int qt    = (id < 256) ? (15 - qi) : (qi - 8);
    const int qbase = qt * BQ;

    const char* kbase = ws + (size_t)bh * KBYTES_PER_HEAD;
    const char* vbase = ws + WS_V_OFF + (size_t)bh * KBYTES_PER_HEAD;

    // hoist Q fragments, pre-scaled into exp2 domain
    f16x8 aq[2];
    {
        const float* qrow = Q + ((size_t)bh * S_ + qbase + w * 16 + l15) * D_;
        #pragma unroll
        for (int kc = 0; kc < 2; ++kc) {
            const float4* p = (const float4*)(qrow + kc * 32 + g * 8);
            float4 x0 = p[0], x1 = p[1];
            f16x8 h;
            h[0] = (_Float16)(x0.x * QSCALE); h[1] = (_Float16)(x0.y * QSCALE);
            h[2] = (_Float16)(x0.z * QSCALE); h[3] = (_Float16)(x0.w * QSCALE);
            h[4] = (_Float16)(x1.x * QSCALE); h[5] = (_Float16)(x1.y * QSCALE);
            h[6] = (_Float16)(x1.z * QSCALE); h[7] = (_Float16)(x1.w * QSCALE);
            aq[kc] = h;
        }
    }

    f32x4 accO[4];
    #pragma unroll
    for (int i = 0; i < 4; ++i) accO[i] = (f32x4){0.f, 0.f, 0.f, 0.f};
    float m_r = -1e30f, l_r = 0.f;
    f32x4 accSA[4], accSB[4];

    const int nt  = 2 * qt + 2;             // 64-wide tiles; last two straddle the diagonal
    const int dqw = qbase + w * 16;         // wave q-row base
    const int dqA = dqw - (nt - 2) * 64;    // diag offsets of the masked pair
    const int dqB = dqw - (nt - 1) * 64;

    // rotating pools. Pair i: K(2i)=kb0 K(2i+1)=kb1, stage K(2i+2)->kb2 K(2i+3)->kb3;
    //                 V(2i-1)=vb0 V(2i)=vb1 V(2i+1)=vb2, stage V(2i+2)->vb3 V(2i+3)->vb4.
    _Float16 *kb0 = &KBuf[0][0], *kb1 = &KBuf[1][0], *kb2 = &KBuf[2][0], *kb3 = &KBuf[3][0];
    _Float16 *vb0 = &VBuf[0][0], *vb1 = &VBuf[1][0], *vb2 = &VBuf[2][0],
             *vb3 = &VBuf[3][0], *vb4 = &VBuf[4][0];

    auto STAGE_K = [&](int t, _Float16* dst) {
        const char* src = kbase + (size_t)t * 8192 + w * 1024 + lane * 16;
        __builtin_amdgcn_global_load_lds((gu32*)src, (lu32*)(dst + w * 512), 16, 0, 0);
    };
    auto STAGE_V = [&](int t, _Float16* dst) {
        const char* src = vbase + (size_t)t * 8192 + w * 1024 + lane * 16;
        __builtin_amdgcn_global_load_lds((gu32*)src, (lu32*)(dst + w * 512), 16, 0, 0);
    };
    auto SYNC = []() {
        asm volatile("s_waitcnt vmcnt(0)" ::: "memory");
        __builtin_amdgcn_s_barrier();
    };
    auto ROT = [&]() {
        _Float16* t0 = kb0; _Float16* t1 = kb1;
        kb0 = kb2; kb1 = kb3; kb2 = t0; kb3 = t1;
        _Float16* u0 = vb0; _Float16* u1 = vb1;
        vb0 = vb2; vb1 = vb3; vb2 = vb4; vb3 = u0; vb4 = u1;
    };

    // prologue: stage tiles 0,1 (V(0)->vb1, V(1)->vb2 per pair-0 expectations)
    STAGE_K(0, kb0); STAGE_V(0, vb1);
    STAGE_K(1, kb1); STAGE_V(1, vb2);

    // ---- unmasked pairs: windows (2i, 2i+1), i = 0..qt-1 — ONE barrier per pair
    for (int i = 0; i < qt; ++i) {
        SYNC();                              // stages of 2i, 2i+1 complete; pool slots free
        STAGE_K(2 * i + 2, kb2); STAGE_V(2 * i + 2, vb3);
        STAGE_K(2 * i + 3, kb3); STAGE_V(2 * i + 3, vb4);
        qk_tile<false>(kb0, aq, accSA, g, l15, 0);
        if (i > 0) smpv_tile<false>(vb0, accSB, accO, m_r, l_r, g, l15, sx, 0);
        qk_tile<false>(kb1, aq, accSB, g, l15, 0);
        smpv_tile<false>(vb1, accSA, accO, m_r, l_r, g, l15, sx, 0);
        ROT();
    }

    // ---- masked pair (tiles nt-2, nt-1)
    SYNC();
    qk_tile<true>(kb0, aq, accSA, g, l15, dqA);
    if (qt > 0) smpv_tile<false>(vb0, accSB, accO, m_r, l_r, g, l15, sx, 0);
    qk_tile<true>(kb1, aq, accSB, g, l15, dqB);
    smpv_tile<true>(vb1, accSA, accO, m_r, l_r, g, l15, sx, dqA);
    ROT();
    // epilogue window: SM+PV(nt-1); V(nt-1) sits at vb0 after rotation
    smpv_tile<true>(vb0, accSB, accO, m_r, l_r, g, l15, sx, dqB);

    // epilogue: finish deferred row-sum (once per kernel), store O
    float l = l_r;
    l += __shfl_xor(l, 16);
    l += __shfl_xor(l, 32);
    const float inv = 1.0f / l;
    float* orow = O + ((size_t)bh * S_ + qbase + w * 16 + l15) * D_;
    #pragma unroll
    for (int d = 0; d < 4; ++d) {
        f32x4 o = accO[d] * inv;
        *(f32x4*)&orow[d * 16 + g * 4] = o;
    }
}

extern "C" void kernel_launch(void* const* d_in, const int* in_sizes, int n_in,
                              void* d_out, int out_size, void* d_ws, size_t ws_size,
                              hipStream_t stream) {
    const float* q = (const float*)d_in[0];
    const float* k = (const float*)d_in[1];
    const float* v = (const float*)d_in[2];
    // d_in[3] (mask) intentionally never read — causality computed in-kernel
    float* o = (float*)d_out;
    char* ws = (char*)d_ws;

    if (ws_size < WS_NEED) return;

    const int kblocks = (B_ * H_ * S_ * 8) / 256;        // 1024
    const int vblocks = B_ * H_ * (S_ / 64);             // 1024
    prep_kv<<<kblocks + vblocks, 256, 0, stream>>>(k, v, ws);
    attn_main<<<(S_ / BQ) * B_ * H_, 512, 0, stream>>>(q, ws, o);
}

// Round 21
// 43.618 us; speedup vs baseline: 1.1699x; 1.0283x over previous
//
#include <hip/hip_runtime.h>

#define B_   2
#define H_   16
#define S_   2048
#define D_   64
#define BQ   128    // q rows per block (16 per wave, 8 waves)
#define NW   8
// fold 1/sqrt(64) * log2(e) into Q so softmax works in exp2 domain
#define QSCALE 0.18033688011112042f
#define DEFER_THR 8.0f

typedef _Float16 f16x8 __attribute__((ext_vector_type(8)));
typedef float    f32x4 __attribute__((ext_vector_type(4)));

typedef const unsigned int __attribute__((address_space(1))) gu32;
typedef unsigned int       __attribute__((address_space(3))) lu32;

#define KBYTES_PER_HEAD (S_ * 128)                       // 256 KB f16 per head per tensor
#define WS_V_OFF ((size_t)B_ * H_ * KBYTES_PER_HEAD)     // 8.4 MB
#define WS_NEED  (2 * WS_V_OFF)

// ---------------- fused prepass: K -> swizzled f16 tiles (unchanged);
// V -> transposed swizzled f16 tiles with PERMUTED granule contents:
// granule kg, position j holds V[k = 32*(kg>>2) + 16*((kg>>1)&1) + 8*(j>>2)
//                                   + 4*(kg&1) + (j&3)]
// (the claimed PV slot<->k map; must match pb packing in smpv_tile).
__global__ __launch_bounds__(256) void prep_kv(const float* __restrict__ K,
                                               const float* __restrict__ V,
                                               char* __restrict__ ws)
{
    if (blockIdx.x < (B_ * H_ * S_ * 8) / 256) {
        const int gidx = blockIdx.x * 256 + threadIdx.x;
        const int gcol = gidx & 7;
        const int srow = gidx >> 3;                      // bh*S + s
        const float4* src = (const float4*)(K + (size_t)srow * D_ + gcol * 8);
        float4 a = src[0], b = src[1];
        f16x8 h;
        h[0] = (_Float16)a.x; h[1] = (_Float16)a.y; h[2] = (_Float16)a.z; h[3] = (_Float16)a.w;
        h[4] = (_Float16)b.x; h[5] = (_Float16)b.y; h[6] = (_Float16)b.z; h[7] = (_Float16)b.w;
        const int s  = srow & (S_ - 1);
        const int bh = srow >> 11;
        size_t off = (size_t)bh * KBYTES_PER_HEAD + (size_t)(s >> 6) * 8192
                   + (s & 63) * 128 + ((gcol ^ (s & 7)) << 4);
        *(f16x8*)(ws + off) = h;
    } else {
        __shared__ _Float16 Vl[64][72];
        const int tile = blockIdx.x - (B_ * H_ * S_ * 8) / 256;  // bh*32 + t
        const int bh = tile >> 5, t = tile & 31;
        const float* vb = V + ((size_t)bh * S_ + t * 64) * D_;
        const int tid = threadIdx.x;
        #pragma unroll
        for (int it = 0; it < 2; ++it) {
            const int row = (tid >> 3) + it * 32;
            const int c8  = (tid & 7) * 8;
            const float4* p = (const float4*)(vb + row * D_ + c8);
            float4 a = p[0], b = p[1];
            f16x8 h;
            h[0] = (_Float16)a.x; h[1] = (_Float16)a.y; h[2] = (_Float16)a.z; h[3] = (_Float16)a.w;
            h[4] = (_Float16)b.x; h[5] = (_Float16)b.y; h[6] = (_Float16)b.z; h[7] = (_Float16)b.w;
            *(f16x8*)&Vl[row][c8] = h;
        }
        __syncthreads();
        char* out = ws + WS_V_OFF + (size_t)bh * KBYTES_PER_HEAD + t * 8192;
        #pragma unroll
        for (int it = 0; it < 2; ++it) {
            const int task = tid + it * 256;
            const int d = task >> 3, kg = task & 7;
            f16x8 h;
            #pragma unroll
            for (int j = 0; j < 8; ++j) {
                const int k = 32 * (kg >> 2) + 16 * ((kg >> 1) & 1)
                            + 8 * (j >> 2) + 4 * (kg & 1) + (j & 3);
                h[j] = Vl[k][d];
            }
            *(f16x8*)(out + d * 128 + ((kg ^ (d & 7)) << 4)) = h;
        }
    }
}

// ---------------- pipeline pieces ----------------
// QK^T swapped, PERMUTED A-rows chosen for BOTH in-register P and conflict-free
// K-reads: lane l15, sub loads K-row
//   kr = 32*(sub>>1) + 8*(sub&1) + 16*(l15>>3) + (l15&7)   (kr&7 = l15&7 = sx)
// By the verified C map (row = 4g+r), lane (g,l15) reg r of accS[sub] then holds
//   k = 32*(sub>>1) + 8*(sub&1) + 16*(g>>1) + 4*(g&1) + r
// which is exactly the claimed PV B-slot map perm32(g, 4*(sub&1)+r) (+32 for sub>=2),
// so exp2 results concat lane-locally into pb0/pb1 (no P LDS roundtrip).
template<bool MASK>
__device__ __forceinline__ void qk_tile(
    const _Float16* __restrict__ Kb, const f16x8 aq[2], f32x4 (&accS)[4],
    int g, int l15, int sx, int dq)
{
    const int rb = 16 * (l15 >> 3) + (l15 & 7);
    #pragma unroll
    for (int s = 0; s < 4; ++s) accS[s] = (f32x4){0.f, 0.f, 0.f, 0.f};
    __builtin_amdgcn_s_setprio(1);
    #pragma unroll
    for (int sub = 0; sub < 4; ++sub) {
        // wave-uniform skip: min k of this sub = 32*(sub>>1) + 8*(sub&1)
        if (MASK && (32 * (sub >> 1) + 8 * (sub & 1) > dq + 15)) continue;
        const int kr = rb + 8 * (sub & 1) + 32 * (sub >> 1);
        #pragma unroll
        for (int kc = 0; kc < 2; ++kc) {
            f16x8 ak = *(const f16x8*)(Kb + (kr * 64 + (((kc * 4 + g) ^ sx) << 3)));
            accS[sub] = __builtin_amdgcn_mfma_f32_16x16x32_f16(ak, aq[kc], accS[sub], 0, 0, 0);
        }
    }
    __builtin_amdgcn_s_setprio(0);
}

// online softmax (exp2 domain, defer-max) + PV, fully in-register P
template<bool MASK>
__device__ __forceinline__ void smpv_tile(
    const _Float16* __restrict__ Vb,
    f32x4 (&accS)[4], f32x4 accO[4], float& m_r, float& l_r,
    int g, int l15, int sx, int dq)
{
    auto msk = [&](int sub, int r) -> float {
        float s = accS[sub][r];
        if (MASK) {
            const int kk = 32 * (sub >> 1) + 8 * (sub & 1)
                         + 16 * (g >> 1) + 4 * (g & 1) + r;
            if (kk > dq + l15) s = -1e30f;
        }
        return s;
    };

    float pmax = -1e30f;
    #pragma unroll
    for (int sub = 0; sub < 4; ++sub)
        #pragma unroll
        for (int r = 0; r < 4; ++r) pmax = fmaxf(pmax, msk(sub, r));

    // defer-max (T13): wave-uniform ballot; common case no cross-lane ops
    if (!__all(pmax <= m_r + DEFER_THR)) {
        float mx = pmax;
        mx = fmaxf(mx, __shfl_xor(mx, 16));
        mx = fmaxf(mx, __shfl_xor(mx, 32));
        const float mnew  = fmaxf(m_r, mx);
        const float alpha = __builtin_amdgcn_exp2f(m_r - mnew);
        l_r *= alpha;
        #pragma unroll
        for (int d = 0; d < 4; ++d)
            #pragma unroll
            for (int r = 0; r < 4; ++r) accO[d][r] *= alpha;
        m_r = mnew;
    }

    // exp2 with (stale-by-<=THR) m_r, packed straight into PV B-fragments
    float rs = 0.f;
    f16x8 pb0, pb1;
    #pragma unroll
    for (int sub = 0; sub < 4; ++sub) {
        float p0 = __builtin_amdgcn_exp2f(msk(sub, 0) - m_r);
        float p1 = __builtin_amdgcn_exp2f(msk(sub, 1) - m_r);
        float p2 = __builtin_amdgcn_exp2f(msk(sub, 2) - m_r);
        float p3 = __builtin_amdgcn_exp2f(msk(sub, 3) - m_r);
        rs += (p0 + p1) + (p2 + p3);
        if (sub == 0) {
            pb0[0] = (_Float16)p0; pb0[1] = (_Float16)p1;
            pb0[2] = (_Float16)p2; pb0[3] = (_Float16)p3;
        } else if (sub == 1) {
            pb0[4] = (_Float16)p0; pb0[5] = (_Float16)p1;
            pb0[6] = (_Float16)p2; pb0[7] = (_Float16)p3;
        } else if (sub == 2) {
            pb1[0] = (_Float16)p0; pb1[1] = (_Float16)p1;
            pb1[2] = (_Float16)p2; pb1[3] = (_Float16)p3;
        } else {
            pb1[4] = (_Float16)p0; pb1[5] = (_Float16)p1;
            pb1[6] = (_Float16)p2; pb1[7] = (_Float16)p3;
        }
    }
    l_r += rs;

    // PV swapped: A = V^T rows (d), B = P^T -> accO[dsub]: d = dsub*16+4g+r, q = l15
    __builtin_amdgcn_s_setprio(1);
    #pragma unroll
    for (int d = 0; d < 4; ++d) {
        f16x8 av0 = *(const f16x8*)(Vb + ((d * 16 + l15) * 64 + (((0 * 4 + g) ^ sx) << 3)));
        accO[d] = __builtin_amdgcn_mfma_f32_16x16x32_f16(av0, pb0, accO[d], 0, 0, 0);
        f16x8 av1 = *(const f16x8*)(Vb + ((d * 16 + l15) * 64 + (((1 * 4 + g) ^ sx) << 3)));
        accO[d] = __builtin_amdgcn_mfma_f32_16x16x32_f16(av1, pb1, accO[d], 0, 0, 0);
    }
    __builtin_amdgcn_s_setprio(0);
}

__global__ __launch_bounds__(512, 4) void attn_main(
    const float* __restrict__ Q, const char* __restrict__ ws, float* __restrict__ O)
{
    // Asymmetric buffer pools: K needs 4 tiles live per pair, V needs 5 (smpv lags
    // one window). 72 KB/block -> 2 blocks/CU, 16 waves.
    __shared__ _Float16 KBuf[4][4096];
    __shared__ _Float16 VBuf[5][4096];

    const int tid  = threadIdx.x;
    const int lane = tid & 63;
    const int w    = tid >> 6;              // wave 0..7
    const int g    = lane >> 4;
    const int l15  = lane & 15;
    const int sx   = l15 & 7;

    // Balanced heavy+light strip pairing with head->XCD affinity (id%8 = bh%8)
    const int id    = blockIdx.x;
    const int bh    = id & 31;
    const int qi    = id >> 5;              // 0..15
    const int qt    = (id < 256) ? (15 - qi) : (qi - 8);
    const int qbase = qt * BQ;

    const char* kbase = ws + (size_t)bh * KBYTES_PER_HEAD;
    const char* vbase = ws + WS_V_OFF + (size_t)bh * KBYTES_PER_HEAD;

    // hoist Q fragments, pre-scaled into exp2 domain
    f16x8 aq[2];
    {
        const float* qrow = Q + ((size_t)bh * S_ + qbase + w * 16 + l15) * D_;
        #pragma unroll
        for (int kc = 0; kc < 2; ++kc) {
            const float4* p = (const float4*)(qrow + kc * 32 + g * 8);
            float4 x0 = p[0], x1 = p[1];
            f16x8 h;
            h[0] = (_Float16)(x0.x * QSCALE); h[1] = (_Float16)(x0.y * QSCALE);
            h[2] = (_Float16)(x0.z * QSCALE); h[3] = (_Float16)(x0.w * QSCALE);
            h[4] = (_Float16)(x1.x * QSCALE); h[5] = (_Float16)(x1.y * QSCALE);
            h[6] = (_Float16)(x1.z * QSCALE); h[7] = (_Float16)(x1.w * QSCALE);
            aq[kc] = h;
        }
    }

    f32x4 accO[4];
    #pragma unroll
    for (int i = 0; i < 4; ++i) accO[i] = (f32x4){0.f, 0.f, 0.f, 0.f};
    float m_r = -1e30f, l_r = 0.f;
    f32x4 accSA[4], accSB[4];

    const int nt  = 2 * qt + 2;             // 64-wide tiles; last two straddle the diagonal
    const int dqw = qbase + w * 16;         // wave q-row base
    const int dqA = dqw - (nt - 2) * 64;    // diag offsets of the masked pair
    const int dqB = dqw - (nt - 1) * 64;

    // rotating pools. Pair i: K(2i)=kb0 K(2i+1)=kb1, stage K(2i+2)->kb2 K(2i+3)->kb3;
    //                 V(2i-1)=vb0 V(2i)=vb1 V(2i+1)=vb2, stage V(2i+2)->vb3 V(2i+3)->vb4.
    _Float16 *kb0 = &KBuf[0][0], *kb1 = &KBuf[1][0], *kb2 = &KBuf[2][0], *kb3 = &KBuf[3][0];
    _Float16 *vb0 = &VBuf[0][0], *vb1 = &VBuf[1][0], *vb2 = &VBuf[2][0],
             *vb3 = &VBuf[3][0], *vb4 = &VBuf[4][0];

    auto STAGE_K = [&](int t, _Float16* dst) {
        const char* src = kbase + (size_t)t * 8192 + w * 1024 + lane * 16;
        __builtin_amdgcn_global_load_lds((gu32*)src, (lu32*)(dst + w * 512), 16, 0, 0);
    };
    auto STAGE_V = [&](int t, _Float16* dst) {
        const char* src = vbase + (size_t)t * 8192 + w * 1024 + lane * 16;
        __builtin_amdgcn_global_load_lds((gu32*)src, (lu32*)(dst + w * 512), 16, 0, 0);
    };
    auto SYNC = []() {
        asm volatile("s_waitcnt vmcnt(0)" ::: "memory");
        __builtin_amdgcn_s_barrier();
    };
    auto ROT = [&]() {
        _Float16* t0 = kb0; _Float16* t1 = kb1;
        kb0 = kb2; kb1 = kb3; kb2 = t0; kb3 = t1;
        _Float16* u0 = vb0; _Float16* u1 = vb1;
        vb0 = vb2; vb1 = vb3; vb2 = vb4; vb3 = u0; vb4 = u1;
    };

    // prologue: stage tiles 0,1 (V(0)->vb1, V(1)->vb2 per pair-0 expectations)
    STAGE_K(0, kb0); STAGE_V(0, vb1);
    STAGE_K(1, kb1); STAGE_V(1, vb2);

    // ---- unmasked pairs: windows (2i, 2i+1), i = 0..qt-1 — ONE barrier per pair
    for (int i = 0; i < qt; ++i) {
        SYNC();                              // stages of 2i, 2i+1 complete; pool slots free
        STAGE_K(2 * i + 2, kb2); STAGE_V(2 * i + 2, vb3);
        STAGE_K(2 * i + 3, kb3); STAGE_V(2 * i + 3, vb4);
        qk_tile<false>(kb0, aq, accSA, g, l15, sx, 0);
        if (i > 0) smpv_tile<false>(vb0, accSB, accO, m_r, l_r, g, l15, sx, 0);
        qk_tile<false>(kb1, aq, accSB, g, l15, sx, 0);
        smpv_tile<false>(vb1, accSA, accO, m_r, l_r, g, l15, sx, 0);
        ROT();
    }

    // ---- masked pair (tiles nt-2, nt-1)
    SYNC();
    qk_tile<true>(kb0, aq, accSA, g, l15, sx, dqA);
    if (qt > 0) smpv_tile<false>(vb0, accSB, accO, m_r, l_r, g, l15, sx, 0);
    qk_tile<true>(kb1, aq, accSB, g, l15, sx, dqB);
    smpv_tile<true>(vb1, accSA, accO, m_r, l_r, g, l15, sx, dqA);
    ROT();
    // epilogue window: SM+PV(nt-1); V(nt-1) sits at vb0 after rotation
    smpv_tile<true>(vb0, accSB, accO, m_r, l_r, g, l15, sx, dqB);

    // epilogue: finish deferred row-sum (once per kernel), store O
    float l = l_r;
    l += __shfl_xor(l, 16);
    l += __shfl_xor(l, 32);
    const float inv = 1.0f / l;
    float* orow = O + ((size_t)bh * S_ + qbase + w * 16 + l15) * D_;
    #pragma unroll
    for (int d = 0; d < 4; ++d) {
        f32x4 o = accO[d] * inv;
        *(f32x4*)&orow[d * 16 + g * 4] = o;
    }
}

extern "C" void kernel_launch(void* const* d_in, const int* in_sizes, int n_in,
                              void* d_out, int out_size, void* d_ws, size_t ws_size,
                              hipStream_t stream) {
    const float* q = (const float*)d_in[0];
    const float* k = (const float*)d_in[1];
    const float* v = (const float*)d_in[2];
    // d_in[3] (mask) intentionally never read — causality computed in-kernel
    float* o = (float*)d_out;
    char* ws = (char*)d_ws;

    if (ws_size < WS_NEED) return;

    const int kblocks = (B_ * H_ * S_ * 8) / 256;        // 1024
    const int vblocks = B_ * H_ * (S_ / 64);             // 1024
    prep_kv<<<kblocks + vblocks, 256, 0, stream>>>(k, v, ws);
    attn_main<<<(S_ / BQ) * B_ * H_, 512, 0, stream>>>(q, ws, o);
}